// Round 1
// baseline (795.216 us; speedup 1.0000x reference)
//
#include <hip/hip_runtime.h>

// ---------------------------------------------------------------------------
// FairnessBranch: router (BN->MLP->softmax) + 16 experts (BN folded ->
// D->128->64->1 sigmoid), weighted sum.  B=65536 D=1024 E=16.
//
// Strategy: fold BNs into first linears (prep), convert to bf16 pre-tiled +
// XOR-swizzled in d_ws, then m97-style MFMA GEMM (global_load_lds width=16,
// 128x128 tiles, 16x16x32 bf16 MFMA) with layers 2/3 fused in-block.
// ---------------------------------------------------------------------------

typedef unsigned short u16;
typedef __attribute__((ext_vector_type(8))) short bf16x8;
typedef __attribute__((ext_vector_type(4))) float f32x4;
typedef __attribute__((ext_vector_type(8))) unsigned short u16x8;
typedef __attribute__((ext_vector_type(4))) unsigned short u16x4;

#define MFMA16(a, b, c) __builtin_amdgcn_mfma_f32_16x16x32_bf16(a, b, c, 0, 0, 0)

#define B_ROWS 65536
#define DIM 1024
#define NE 16
#define EPS 1e-5f

// fp32 -> bf16 round-to-nearest-even (no NaN inputs here)
__device__ inline u16 f2bf(float f) {
    union { float f; unsigned u; } c; c.f = f;
    unsigned u = c.u;
    return (u16)((u + 0x7fffu + ((u >> 16) & 1u)) >> 16);
}

// async global->LDS, 16B per lane. lds dest must be wave-uniform base.
__device__ inline void gload16(const u16* g, u16* s) {
    __builtin_amdgcn_global_load_lds(
        (const __attribute__((address_space(1))) unsigned int*)g,
        (__attribute__((address_space(3))) unsigned int*)s,
        16, 0, 0);
}

// ---------------------------------------------------------------------------
// prep kernels
// ---------------------------------------------------------------------------

// x [B][D] fp32 -> bf16, tiled [rb(512)][kc(16)][r(128)][64] with 16B-block
// XOR swizzle (phys_blk = logical_blk ^ (r&7)) so GEMM ds_read_b128 is clean.
__global__ void prep_x(const float* __restrict__ x, u16* __restrict__ xs_g) {
    int t = blockIdx.x * 256 + threadIdx.x;           // B*128 threads
    int b = t >> 7, blk = t & 127;
    const float* xp = x + ((size_t)b << 10) + (blk << 3);
    float4 f0 = *(const float4*)xp;
    float4 f1 = *(const float4*)(xp + 4);
    u16x8 u;
    u[0] = f2bf(f0.x); u[1] = f2bf(f0.y); u[2] = f2bf(f0.z); u[3] = f2bf(f0.w);
    u[4] = f2bf(f1.x); u[5] = f2bf(f1.y); u[6] = f2bf(f1.z); u[7] = f2bf(f1.w);
    int rb = b >> 7, r = b & 127, kc = blk >> 3, lb = blk & 7;
    int phys = lb ^ (r & 7);
    *(u16x8*)&xs_g[(((size_t)(rb * 16 + kc) * 128 + r) << 6) + phys * 8] = u;
}

// W1_eff^T bf16: w1s[e][kc][h(128)][64 swizzled]; content = eW1[e][d][h]*scale[e][d]
__global__ void prep_w1s(const float* __restrict__ eW1, const float* __restrict__ eg,
                         const float* __restrict__ ev, u16* __restrict__ w1s) {
    int t = blockIdx.x * 256 + threadIdx.x;           // 16*16*128*8 threads
    int p = t & 7, r = (t >> 3) & 127, kc = (t >> 10) & 15, e = t >> 14;
    int lb = p ^ (r & 7);
    u16x8 u;
#pragma unroll
    for (int j = 0; j < 8; ++j) {
        int d = kc * 64 + lb * 8 + j;
        float sc = eg[e * 1024 + d] * rsqrtf(ev[e * 1024 + d] + EPS);
        u[j] = f2bf(eW1[((size_t)e * 1024 + d) * 128 + r] * sc);
    }
    *(u16x8*)&w1s[((size_t)((e * 16 + kc) * 128 + r) << 6) + p * 8] = u;
}

// b1_eff[e][h] = eb1 + sum_d shift[e][d]*eW1[e][d][h]; one wave per (e,h)
__global__ void prep_b1(const float* __restrict__ eW1, const float* __restrict__ eg,
                        const float* __restrict__ eb, const float* __restrict__ em,
                        const float* __restrict__ ev, const float* __restrict__ eb1,
                        float* __restrict__ b1e) {
    int wave = threadIdx.x >> 6, lane = threadIdx.x & 63;
    int g = blockIdx.x * 4 + wave;                    // 2048 waves
    int e = g >> 7, h = g & 127;
    float s = 0.f;
    for (int d = lane; d < 1024; d += 64) {
        float sc = eg[e * 1024 + d] * rsqrtf(ev[e * 1024 + d] + EPS);
        float sh = eb[e * 1024 + d] - em[e * 1024 + d] * sc;
        s += sh * eW1[((size_t)e * 1024 + d) * 128 + h];
    }
#pragma unroll
    for (int m = 1; m < 64; m <<= 1) s += __shfl_xor(s, m, 64);
    if (lane == 0) b1e[e * 128 + h] = eb1[e * 128 + h] + s;
}

// router W1_eff^T bf16: rw1s[kc][j(64)][64 swizzled]
__global__ void prep_rw1s(const float* __restrict__ rW1, const float* __restrict__ rg,
                          const float* __restrict__ rv, u16* __restrict__ rw1s) {
    int t = blockIdx.x * 256 + threadIdx.x;           // 16*64*8 threads
    int p = t & 7, r = (t >> 3) & 63, kc = t >> 9;
    int lb = p ^ (r & 7);
    u16x8 u;
#pragma unroll
    for (int j = 0; j < 8; ++j) {
        int d = kc * 64 + lb * 8 + j;
        float sc = rg[d] * rsqrtf(rv[d] + EPS);
        u[j] = f2bf(rW1[d * 64 + r] * sc);
    }
    *(u16x8*)&rw1s[((kc * 64 + r) << 6) + p * 8] = u;
}

// rb1_eff[j] = rb1[j] + sum_d shift[d]*rW1[d][j]; one wave per j
__global__ void prep_rb1(const float* __restrict__ rW1, const float* __restrict__ rg,
                         const float* __restrict__ rbta, const float* __restrict__ rm,
                         const float* __restrict__ rv, const float* __restrict__ rb1,
                         float* __restrict__ rb1e) {
    int wave = threadIdx.x >> 6, lane = threadIdx.x & 63;
    int j = blockIdx.x * 4 + wave;                    // 64 waves
    float s = 0.f;
    for (int d = lane; d < 1024; d += 64) {
        float sc = rg[d] * rsqrtf(rv[d] + EPS);
        float sh = rbta[d] - rm[d] * sc;
        s += sh * rW1[d * 64 + j];
    }
#pragma unroll
    for (int m = 1; m < 64; m <<= 1) s += __shfl_xor(s, m, 64);
    if (lane == 0) rb1e[j] = rb1[j] + s;
}

// W2^T bf16: w2s[e][j(64)][128 swizzled]; content = eW2[e][h][j]
__global__ void prep_w2s(const float* __restrict__ eW2, u16* __restrict__ w2s) {
    int t = blockIdx.x * 256 + threadIdx.x;           // 16*64*16 threads
    int p = t & 15, j = (t >> 4) & 63, e = t >> 10;
    int lb = p ^ (j & 7);
    int h0 = lb * 8;
    u16x8 u;
#pragma unroll
    for (int jj = 0; jj < 8; ++jj)
        u[jj] = f2bf(eW2[((size_t)e * 128 + h0 + jj) * 64 + j]);
    *(u16x8*)&w2s[((e * 64 + j) << 7) + p * 8] = u;
}

// ---------------------------------------------------------------------------
// expert kernel: per block = (row-block rb of 128 rows, expert e)
// layer1 MFMA (C[h][m] = W1t x^T), fused relu->LDS, layer2 MFMA, layer3 shfl.
// ---------------------------------------------------------------------------
__global__ __launch_bounds__(256) void expert_kernel(
    const u16* __restrict__ xs_g, const u16* __restrict__ w1s,
    const float* __restrict__ b1e, const u16* __restrict__ w2s,
    const float* __restrict__ eb2, const float* __restrict__ eW3,
    const float* __restrict__ eb3, float* __restrict__ out_eo) {
    __shared__ __align__(16) u16 sA[16384];   // 32KB: xs[8192] | wt[8192]; then h1L[128][128]
    __shared__ __align__(16) u16 sW2[8192];   // 16KB: w2t[64][128]

    int tid = threadIdx.x;
    int wave = tid >> 6, lane = tid & 63;
    int quad = lane >> 4, l15 = lane & 15;
    int bid = blockIdx.x;
    int e = bid & 15, rb = bid >> 4;
    int wm = wave & 1, wn = wave >> 1;

    f32x4 acc[4][4] = {};
    const u16* xg_base = xs_g + (size_t)rb * 131072;   // 16*8192
    const u16* wg_base = w1s + (size_t)e * 131072;

    for (int kc = 0; kc < 16; ++kc) {
        const u16* xg = xg_base + kc * 8192;
        const u16* wg = wg_base + kc * 8192;
        int so = wave * 2048;
#pragma unroll
        for (int i = 0; i < 4; ++i) {
            gload16(xg + so + i * 512 + lane * 8, &sA[so + i * 512]);
            gload16(wg + so + i * 512 + lane * 8, &sA[8192 + so + i * 512]);
        }
        __syncthreads();
#pragma unroll
        for (int ks = 0; ks < 2; ++ks) {
            bf16x8 af[4], bfr[4];
#pragma unroll
            for (int s = 0; s < 4; ++s) {
                int h = wm * 64 + s * 16 + l15;
                int phys = (ks * 4 + quad) ^ (h & 7);
                af[s] = *(const bf16x8*)&sA[8192 + h * 64 + phys * 8];
            }
#pragma unroll
            for (int t = 0; t < 4; ++t) {
                int m = wn * 64 + t * 16 + l15;
                int phys = (ks * 4 + quad) ^ (m & 7);
                bfr[t] = *(const bf16x8*)&sA[m * 64 + phys * 8];
            }
#pragma unroll
            for (int s = 0; s < 4; ++s)
#pragma unroll
                for (int t = 0; t < 4; ++t)
                    acc[s][t] = MFMA16(af[s], bfr[t], acc[s][t]);
        }
        __syncthreads();
    }

    // stage W2t (async, waited by next barrier)
    {
        const u16* wg2 = w2s + e * 8192;
        int so = wave * 2048;
#pragma unroll
        for (int i = 0; i < 4; ++i)
            gload16(wg2 + so + i * 512 + lane * 8, &sW2[so + i * 512]);
    }
    // h1L[m][h] = relu(acc + b1), bf16, packed 4 (lane's 4 regs = 4 consec h)
#pragma unroll
    for (int s = 0; s < 4; ++s) {
        int h0 = wm * 64 + s * 16 + quad * 4;
        float4 bv = *(const float4*)&b1e[e * 128 + h0];
        float bva[4] = {bv.x, bv.y, bv.z, bv.w};
#pragma unroll
        for (int t = 0; t < 4; ++t) {
            int m = wn * 64 + t * 16 + l15;
            u16x4 pk;
#pragma unroll
            for (int r = 0; r < 4; ++r) {
                float v = acc[s][t][r] + bva[r];
                pk[r] = f2bf(fmaxf(v, 0.f));
            }
            int phys = (h0 >> 3) ^ (m & 7);
            *(u16x4*)&sA[m * 128 + phys * 8 + (h0 & 7)] = pk;
        }
    }
    __syncthreads();

    // layer 2: C2[m][j] = h1L[m][:] . W2[:, j]
    f32x4 acc2[2][4] = {};
#pragma unroll
    for (int ks = 0; ks < 4; ++ks) {
        bf16x8 a2[2], b2[4];
#pragma unroll
        for (int s = 0; s < 2; ++s) {
            int m = wave * 32 + s * 16 + l15;
            int phys = (ks * 4 + quad) ^ (m & 7);
            a2[s] = *(const bf16x8*)&sA[m * 128 + phys * 8];
        }
#pragma unroll
        for (int t = 0; t < 4; ++t) {
            int j = t * 16 + l15;
            int phys = (ks * 4 + quad) ^ (j & 7);
            b2[t] = *(const bf16x8*)&sW2[j * 128 + phys * 8];
        }
#pragma unroll
        for (int s = 0; s < 2; ++s)
#pragma unroll
            for (int t = 0; t < 4; ++t)
                acc2[s][t] = MFMA16(a2[s], b2[t], acc2[s][t]);
    }

    // layer 3 + sigmoid
    float b2v[4], w3v[4];
#pragma unroll
    for (int t = 0; t < 4; ++t) {
        int j = t * 16 + l15;
        b2v[t] = eb2[e * 64 + j];
        w3v[t] = eW3[e * 64 + j];
    }
    float be3 = eb3[e];
#pragma unroll
    for (int s = 0; s < 2; ++s) {
        float sv[4] = {0.f, 0.f, 0.f, 0.f};
#pragma unroll
        for (int t = 0; t < 4; ++t)
#pragma unroll
            for (int r = 0; r < 4; ++r) {
                float v = acc2[s][t][r] + b2v[t];
                sv[r] += fmaxf(v, 0.f) * w3v[t];
            }
#pragma unroll
        for (int mask = 1; mask < 16; mask <<= 1)
#pragma unroll
            for (int r = 0; r < 4; ++r) sv[r] += __shfl_xor(sv[r], mask, 64);
        if (l15 == 0) {
#pragma unroll
            for (int r = 0; r < 4; ++r) {
                int m = wave * 32 + s * 16 + quad * 4 + r;
                float z = sv[r] + be3;
                out_eo[(size_t)(rb * 128 + m) * 16 + e] = 1.f / (1.f + __expf(-z));
            }
        }
    }
}

// ---------------------------------------------------------------------------
// router kernel: 128-row blocks; MFMA layer1 (N=64), fp32 VALU layers 2/3 +
// softmax over 16 experts.
// ---------------------------------------------------------------------------
__global__ __launch_bounds__(256) void router_kernel(
    const u16* __restrict__ xs_g, const u16* __restrict__ rw1s,
    const float* __restrict__ rb1e, const float* __restrict__ rW2,
    const float* __restrict__ rb2, const float* __restrict__ rW3,
    const float* __restrict__ rb3, float* __restrict__ out_rw) {
    __shared__ __align__(16) char region0[34816];  // stage xs 16KB | rw1 8KB; then h_r[128][68] f32
    __shared__ __align__(16) float h2s[128 * 36];

    u16* xs_l = (u16*)region0;
    u16* rw_l = (u16*)(region0 + 16384);
    float* h_r = (float*)region0;

    int tid = threadIdx.x;
    int wave = tid >> 6, lane = tid & 63;
    int quad = lane >> 4, l15 = lane & 15;
    int rb = blockIdx.x;

    f32x4 acc[4][2] = {};
    const u16* xg_base = xs_g + (size_t)rb * 131072;

    for (int kc = 0; kc < 16; ++kc) {
        const u16* xg = xg_base + kc * 8192;
        const u16* rg = rw1s + kc * 4096;
        int so = wave * 2048;
#pragma unroll
        for (int i = 0; i < 4; ++i)
            gload16(xg + so + i * 512 + lane * 8, &xs_l[so + i * 512]);
        int so2 = wave * 1024;
#pragma unroll
        for (int i = 0; i < 2; ++i)
            gload16(rg + so2 + i * 512 + lane * 8, &rw_l[so2 + i * 512]);
        __syncthreads();
#pragma unroll
        for (int ks = 0; ks < 2; ++ks) {
            bf16x8 af[4], bfr[2];
#pragma unroll
            for (int s = 0; s < 4; ++s) {
                int j = s * 16 + l15;
                int phys = (ks * 4 + quad) ^ (j & 7);
                af[s] = *(const bf16x8*)&rw_l[j * 64 + phys * 8];
            }
#pragma unroll
            for (int t = 0; t < 2; ++t) {
                int m = wave * 32 + t * 16 + l15;
                int phys = (ks * 4 + quad) ^ (m & 7);
                bfr[t] = *(const bf16x8*)&xs_l[m * 64 + phys * 8];
            }
#pragma unroll
            for (int s = 0; s < 4; ++s)
#pragma unroll
                for (int t = 0; t < 2; ++t)
                    acc[s][t] = MFMA16(af[s], bfr[t], acc[s][t]);
        }
        __syncthreads();
    }

    // epilogue: h_r[m][j] fp32 (stride 68 for bank spread + 16B align)
#pragma unroll
    for (int s = 0; s < 4; ++s) {
        int j0 = s * 16 + quad * 4;
        float4 bv = *(const float4*)&rb1e[j0];
#pragma unroll
        for (int t = 0; t < 2; ++t) {
            int m = wave * 32 + t * 16 + l15;
            float4 hv;
            hv.x = fmaxf(acc[s][t][0] + bv.x, 0.f);
            hv.y = fmaxf(acc[s][t][1] + bv.y, 0.f);
            hv.z = fmaxf(acc[s][t][2] + bv.z, 0.f);
            hv.w = fmaxf(acc[s][t][3] + bv.w, 0.f);
            *(float4*)&h_r[m * 68 + j0] = hv;
        }
    }
    __syncthreads();

    // layer 2 (64->32), fp32 VALU; rW2 loads are wave-uniform (scalarized)
    {
        int m = tid & 127, qg = tid >> 7;
        float h2r[16];
#pragma unroll
        for (int k = 0; k < 16; ++k) h2r[k] = 0.f;
        for (int i = 0; i < 64; ++i) {
            float hv = h_r[m * 68 + i];
            const float4* wrow = (const float4*)&rW2[i * 32 + qg * 16];
            float w[16];
            *(float4*)&w[0] = wrow[0];
            *(float4*)&w[4] = wrow[1];
            *(float4*)&w[8] = wrow[2];
            *(float4*)&w[12] = wrow[3];
#pragma unroll
            for (int k = 0; k < 16; ++k) h2r[k] += hv * w[k];
        }
#pragma unroll
        for (int k = 0; k < 16; ++k)
            h2r[k] = fmaxf(h2r[k] + rb2[qg * 16 + k], 0.f);
#pragma unroll
        for (int k = 0; k < 16; k += 4)
            *(float4*)&h2s[m * 36 + qg * 16 + k] = *(float4*)&h2r[k];
    }
    __syncthreads();

    // layer 3 (32->16) + softmax
    if (tid < 128) {
        int mm = tid;
        float lg[16];
#pragma unroll
        for (int o = 0; o < 16; ++o) lg[o] = 0.f;
        for (int q = 0; q < 32; ++q) {
            float hv = h2s[mm * 36 + q];
            const float4* wr = (const float4*)&rW3[q * 16];
            float w[16];
            *(float4*)&w[0] = wr[0];
            *(float4*)&w[4] = wr[1];
            *(float4*)&w[8] = wr[2];
            *(float4*)&w[12] = wr[3];
#pragma unroll
            for (int o = 0; o < 16; ++o) lg[o] += hv * w[o];
        }
#pragma unroll
        for (int o = 0; o < 16; ++o) lg[o] += rb3[o];
        float mx = lg[0];
#pragma unroll
        for (int o = 1; o < 16; ++o) mx = fmaxf(mx, lg[o]);
        float ss = 0.f;
#pragma unroll
        for (int o = 0; o < 16; ++o) { lg[o] = __expf(lg[o] - mx); ss += lg[o]; }
        float inv = 1.f / ss;
        size_t base = (size_t)(rb * 128 + mm) * 16;
#pragma unroll
        for (int o = 0; o < 16; o += 4) {
            float4 v;
            v.x = lg[o] * inv; v.y = lg[o + 1] * inv;
            v.z = lg[o + 2] * inv; v.w = lg[o + 3] * inv;
            *(float4*)&out_rw[base + o] = v;
        }
    }
}

// weighted_pred[b] = sum_e rw[b][e]*eo[b][e]
__global__ void combine_kernel(const float* __restrict__ rw, const float* __restrict__ eo,
                               float* __restrict__ wp) {
    int b = blockIdx.x * 256 + threadIdx.x;
    const float4* r4 = (const float4*)(rw + (size_t)b * 16);
    const float4* o4 = (const float4*)(eo + (size_t)b * 16);
    float s = 0.f;
#pragma unroll
    for (int k = 0; k < 4; ++k) {
        float4 r = r4[k], o = o4[k];
        s += r.x * o.x + r.y * o.y + r.z * o.z + r.w * o.w;
    }
    wp[b] = s;
}

// ---------------------------------------------------------------------------

extern "C" void kernel_launch(void* const* d_in, const int* in_sizes, int n_in,
                              void* d_out, int out_size, void* d_ws, size_t ws_size,
                              hipStream_t stream) {
    const float* x       = (const float*)d_in[0];
    const float* r_gamma = (const float*)d_in[1];
    const float* r_beta  = (const float*)d_in[2];
    const float* r_mean  = (const float*)d_in[3];
    const float* r_var   = (const float*)d_in[4];
    const float* rW1     = (const float*)d_in[5];
    const float* rb1     = (const float*)d_in[6];
    const float* rW2     = (const float*)d_in[7];
    const float* rb2     = (const float*)d_in[8];
    const float* rW3     = (const float*)d_in[9];
    const float* rb3     = (const float*)d_in[10];
    const float* e_gamma = (const float*)d_in[11];
    const float* e_beta  = (const float*)d_in[12];
    const float* e_mean  = (const float*)d_in[13];
    const float* e_var   = (const float*)d_in[14];
    const float* eW1     = (const float*)d_in[15];
    const float* eb1     = (const float*)d_in[16];
    const float* eW2     = (const float*)d_in[17];
    const float* eb2     = (const float*)d_in[18];
    const float* eW3     = (const float*)d_in[19];
    const float* eb3     = (const float*)d_in[20];

    char* ws = (char*)d_ws;
    u16* xs_g   = (u16*)ws;                          // 134217728 B
    u16* w1s    = (u16*)(ws + 134217728);            // 4194304 B
    u16* rw1s   = (u16*)(ws + 138412032);            // 131072 B
    u16* w2s    = (u16*)(ws + 138543104);            // 262144 B
    float* b1e  = (float*)(ws + 138805248);          // 8192 B
    float* rb1e = (float*)(ws + 138813440);          // 256 B

    float* out_wp = (float*)d_out;
    float* out_rw = out_wp + B_ROWS;
    float* out_eo = out_rw + (size_t)B_ROWS * NE;

    prep_x<<<32768, 256, 0, stream>>>(x, xs_g);
    prep_w1s<<<1024, 256, 0, stream>>>(eW1, e_gamma, e_var, w1s);
    prep_b1<<<512, 256, 0, stream>>>(eW1, e_gamma, e_beta, e_mean, e_var, eb1, b1e);
    prep_rw1s<<<32, 256, 0, stream>>>(rW1, r_gamma, r_var, rw1s);
    prep_rb1<<<16, 256, 0, stream>>>(rW1, r_gamma, r_beta, r_mean, r_var, rb1, rb1e);
    prep_w2s<<<64, 256, 0, stream>>>(eW2, w2s);

    router_kernel<<<512, 256, 0, stream>>>(xs_g, rw1s, rb1e, rW2, rb2, rW3, rb3, out_rw);
    expert_kernel<<<8192, 256, 0, stream>>>(xs_g, w1s, b1e, w2s, eb2, eW3, eb3, out_eo);
    combine_kernel<<<256, 256, 0, stream>>>(out_rw, out_eo, out_wp);
}

// Round 2
// 790.410 us; speedup vs baseline: 1.0061x; 1.0061x over previous
//
#include <hip/hip_runtime.h>

// ---------------------------------------------------------------------------
// FairnessBranch: router (BN->MLP->softmax) + 16 experts (BN folded ->
// D->128->64->1 sigmoid), weighted sum.  B=65536 D=1024 E=16.
//
// R2: dispatch consolidation. 9 launches -> 3:
//   prep_all (prep_x + 5 weight preps as block-ranges, latency hides under
//   prep_x's BW floor), fused_main (router blocks 0..511 + expert blocks
//   512..8703, block-uniform branch), combine. Compute bodies identical to R1.
// ---------------------------------------------------------------------------

typedef unsigned short u16;
typedef __attribute__((ext_vector_type(8))) short bf16x8;
typedef __attribute__((ext_vector_type(4))) float f32x4;
typedef __attribute__((ext_vector_type(8))) unsigned short u16x8;
typedef __attribute__((ext_vector_type(4))) unsigned short u16x4;

#define MFMA16(a, b, c) __builtin_amdgcn_mfma_f32_16x16x32_bf16(a, b, c, 0, 0, 0)

#define B_ROWS 65536
#define DIM 1024
#define NE 16
#define EPS 1e-5f

// fp32 -> bf16 round-to-nearest-even
__device__ inline u16 f2bf(float f) {
    union { float f; unsigned u; } c; c.f = f;
    unsigned u = c.u;
    return (u16)((u + 0x7fffu + ((u >> 16) & 1u)) >> 16);
}

// async global->LDS, 16B per lane. lds dest must be wave-uniform base.
__device__ inline void gload16(const u16* g, u16* s) {
    __builtin_amdgcn_global_load_lds(
        (const __attribute__((address_space(1))) unsigned int*)g,
        (__attribute__((address_space(3))) unsigned int*)s,
        16, 0, 0);
}

// ---------------------------------------------------------------------------
// prep bodies (as __device__ fns; grid ranges inside prep_all)
// ---------------------------------------------------------------------------

// x [B][D] fp32 -> bf16, tiled [rb(512)][kc(16)][r(128)][64] with 16B-block
// XOR swizzle (phys_blk = logical_blk ^ (r&7)).
__device__ void body_prep_x(int t, const float* __restrict__ x, u16* __restrict__ xs_g) {
    int b = t >> 7, blk = t & 127;
    const float* xp = x + ((size_t)b << 10) + (blk << 3);
    float4 f0 = *(const float4*)xp;
    float4 f1 = *(const float4*)(xp + 4);
    u16x8 u;
    u[0] = f2bf(f0.x); u[1] = f2bf(f0.y); u[2] = f2bf(f0.z); u[3] = f2bf(f0.w);
    u[4] = f2bf(f1.x); u[5] = f2bf(f1.y); u[6] = f2bf(f1.z); u[7] = f2bf(f1.w);
    int rb = b >> 7, r = b & 127, kc = blk >> 3, lb = blk & 7;
    int phys = lb ^ (r & 7);
    *(u16x8*)&xs_g[(((size_t)(rb * 16 + kc) * 128 + r) << 6) + phys * 8] = u;
}

// W1_eff^T bf16: w1s[e][kc][h(128)][64 swizzled]
__device__ void body_prep_w1s(int t, const float* __restrict__ eW1, const float* __restrict__ eg,
                              const float* __restrict__ ev, u16* __restrict__ w1s) {
    int p = t & 7, r = (t >> 3) & 127, kc = (t >> 10) & 15, e = t >> 14;
    int lb = p ^ (r & 7);
    u16x8 u;
#pragma unroll
    for (int j = 0; j < 8; ++j) {
        int d = kc * 64 + lb * 8 + j;
        float sc = eg[e * 1024 + d] * rsqrtf(ev[e * 1024 + d] + EPS);
        u[j] = f2bf(eW1[((size_t)e * 1024 + d) * 128 + r] * sc);
    }
    *(u16x8*)&w1s[((size_t)((e * 16 + kc) * 128 + r) << 6) + p * 8] = u;
}

// b1_eff[e][h] = eb1 + sum_d shift[e][d]*eW1[e][d][h]; one wave per (e,h)
__device__ void body_prep_b1(int g, int lane, const float* __restrict__ eW1,
                             const float* __restrict__ eg, const float* __restrict__ eb,
                             const float* __restrict__ em, const float* __restrict__ ev,
                             const float* __restrict__ eb1, float* __restrict__ b1e) {
    int e = g >> 7, h = g & 127;
    float s = 0.f;
    for (int d = lane; d < 1024; d += 64) {
        float sc = eg[e * 1024 + d] * rsqrtf(ev[e * 1024 + d] + EPS);
        float sh = eb[e * 1024 + d] - em[e * 1024 + d] * sc;
        s += sh * eW1[((size_t)e * 1024 + d) * 128 + h];
    }
#pragma unroll
    for (int m = 1; m < 64; m <<= 1) s += __shfl_xor(s, m, 64);
    if (lane == 0) b1e[e * 128 + h] = eb1[e * 128 + h] + s;
}

// router W1_eff^T bf16: rw1s[kc][j(64)][64 swizzled]
__device__ void body_prep_rw1s(int t, const float* __restrict__ rW1, const float* __restrict__ rg,
                               const float* __restrict__ rv, u16* __restrict__ rw1s) {
    int p = t & 7, r = (t >> 3) & 63, kc = t >> 9;
    int lb = p ^ (r & 7);
    u16x8 u;
#pragma unroll
    for (int j = 0; j < 8; ++j) {
        int d = kc * 64 + lb * 8 + j;
        float sc = rg[d] * rsqrtf(rv[d] + EPS);
        u[j] = f2bf(rW1[d * 64 + r] * sc);
    }
    *(u16x8*)&rw1s[((kc * 64 + r) << 6) + p * 8] = u;
}

// rb1_eff[j] = rb1[j] + sum_d shift[d]*rW1[d][j]; one wave per j
__device__ void body_prep_rb1(int j, int lane, const float* __restrict__ rW1,
                              const float* __restrict__ rg, const float* __restrict__ rbta,
                              const float* __restrict__ rm, const float* __restrict__ rv,
                              const float* __restrict__ rb1, float* __restrict__ rb1e) {
    float s = 0.f;
    for (int d = lane; d < 1024; d += 64) {
        float sc = rg[d] * rsqrtf(rv[d] + EPS);
        float sh = rbta[d] - rm[d] * sc;
        s += sh * rW1[d * 64 + j];
    }
#pragma unroll
    for (int m = 1; m < 64; m <<= 1) s += __shfl_xor(s, m, 64);
    if (lane == 0) rb1e[j] = rb1[j] + s;
}

// W2^T bf16: w2s[e][j(64)][128 swizzled]
__device__ void body_prep_w2s(int t, const float* __restrict__ eW2, u16* __restrict__ w2s) {
    int p = t & 15, j = (t >> 4) & 63, e = t >> 10;
    int lb = p ^ (j & 7);
    int h0 = lb * 8;
    u16x8 u;
#pragma unroll
    for (int jj = 0; jj < 8; ++jj)
        u[jj] = f2bf(eW2[((size_t)e * 128 + h0 + jj) * 64 + j]);
    *(u16x8*)&w2s[((e * 64 + j) << 7) + p * 8] = u;
}

// grid layout: [0,32768) prep_x | [32768,33792) w1s | [33792,34304) b1
//              [34304,34336) rw1s | [34336,34352) rb1 | [34352,34416) w2s
__global__ __launch_bounds__(256) void prep_all(
    const float* __restrict__ x, u16* __restrict__ xs_g,
    const float* __restrict__ eW1, const float* __restrict__ eg,
    const float* __restrict__ eb, const float* __restrict__ em,
    const float* __restrict__ ev, const float* __restrict__ eb1,
    u16* __restrict__ w1s, float* __restrict__ b1e,
    const float* __restrict__ rW1, const float* __restrict__ rg,
    const float* __restrict__ rbta, const float* __restrict__ rm,
    const float* __restrict__ rv, const float* __restrict__ rb1,
    u16* __restrict__ rw1s, float* __restrict__ rb1e,
    const float* __restrict__ eW2, u16* __restrict__ w2s) {
    int bid = blockIdx.x, tid = threadIdx.x;
    if (bid < 32768) {
        body_prep_x(bid * 256 + tid, x, xs_g);
    } else if (bid < 33792) {
        body_prep_w1s((bid - 32768) * 256 + tid, eW1, eg, ev, w1s);
    } else if (bid < 34304) {
        body_prep_b1((bid - 33792) * 4 + (tid >> 6), tid & 63, eW1, eg, eb, em, ev, eb1, b1e);
    } else if (bid < 34336) {
        body_prep_rw1s((bid - 34304) * 256 + tid, rW1, rg, rv, rw1s);
    } else if (bid < 34352) {
        body_prep_rb1((bid - 34336) * 4 + (tid >> 6), tid & 63, rW1, rg, rbta, rm, rv, rb1, rb1e);
    } else {
        body_prep_w2s((bid - 34352) * 256 + tid, eW2, w2s);
    }
}

// ---------------------------------------------------------------------------
// fused main kernel: blocks [0,512) router, [512,8704) experts.
// ---------------------------------------------------------------------------
__global__ __launch_bounds__(256) void fused_main(
    const u16* __restrict__ xs_g, const u16* __restrict__ w1s,
    const float* __restrict__ b1e, const u16* __restrict__ w2s,
    const float* __restrict__ eb2, const float* __restrict__ eW3,
    const float* __restrict__ eb3, float* __restrict__ out_eo,
    const u16* __restrict__ rw1s, const float* __restrict__ rb1e,
    const float* __restrict__ rW2, const float* __restrict__ rb2,
    const float* __restrict__ rW3, const float* __restrict__ rb3,
    float* __restrict__ out_rw) {
    // union: expert uses 48KB (sA 32K | sW2 16K); router uses 52KB
    // (staging/h_r 34816 | h2s 18432). 53248B -> 3 blocks/CU either way.
    __shared__ __align__(16) char smem[53248];

    int tid = threadIdx.x;
    int wave = tid >> 6, lane = tid & 63;
    int quad = lane >> 4, l15 = lane & 15;

    if (blockIdx.x >= 512) {
        // ------------------------- expert path -------------------------
        u16* sA = (u16*)smem;             // 32KB: xs[8192] | wt[8192]; then h1L[128][128]
        u16* sW2 = (u16*)(smem + 32768);  // 16KB: w2t[64][128]
        int bid = blockIdx.x - 512;
        int e = bid & 15, rb = bid >> 4;
        int wm = wave & 1, wn = wave >> 1;

        f32x4 acc[4][4] = {};
        const u16* xg_base = xs_g + (size_t)rb * 131072;
        const u16* wg_base = w1s + (size_t)e * 131072;

        for (int kc = 0; kc < 16; ++kc) {
            const u16* xg = xg_base + kc * 8192;
            const u16* wg = wg_base + kc * 8192;
            int so = wave * 2048;
#pragma unroll
            for (int i = 0; i < 4; ++i) {
                gload16(xg + so + i * 512 + lane * 8, &sA[so + i * 512]);
                gload16(wg + so + i * 512 + lane * 8, &sA[8192 + so + i * 512]);
            }
            __syncthreads();
#pragma unroll
            for (int ks = 0; ks < 2; ++ks) {
                bf16x8 af[4], bfr[4];
#pragma unroll
                for (int s = 0; s < 4; ++s) {
                    int h = wm * 64 + s * 16 + l15;
                    int phys = (ks * 4 + quad) ^ (h & 7);
                    af[s] = *(const bf16x8*)&sA[8192 + h * 64 + phys * 8];
                }
#pragma unroll
                for (int t = 0; t < 4; ++t) {
                    int m = wn * 64 + t * 16 + l15;
                    int phys = (ks * 4 + quad) ^ (m & 7);
                    bfr[t] = *(const bf16x8*)&sA[m * 64 + phys * 8];
                }
#pragma unroll
                for (int s = 0; s < 4; ++s)
#pragma unroll
                    for (int t = 0; t < 4; ++t)
                        acc[s][t] = MFMA16(af[s], bfr[t], acc[s][t]);
            }
            __syncthreads();
        }

        // stage W2t (async, waited by next barrier)
        {
            const u16* wg2 = w2s + e * 8192;
            int so = wave * 2048;
#pragma unroll
            for (int i = 0; i < 4; ++i)
                gload16(wg2 + so + i * 512 + lane * 8, &sW2[so + i * 512]);
        }
        // h1L[m][h] = relu(acc + b1), bf16 packed 4
#pragma unroll
        for (int s = 0; s < 4; ++s) {
            int h0 = wm * 64 + s * 16 + quad * 4;
            float4 bv = *(const float4*)&b1e[e * 128 + h0];
            float bva[4] = {bv.x, bv.y, bv.z, bv.w};
#pragma unroll
            for (int t = 0; t < 4; ++t) {
                int m = wn * 64 + t * 16 + l15;
                u16x4 pk;
#pragma unroll
                for (int r = 0; r < 4; ++r) {
                    float v = acc[s][t][r] + bva[r];
                    pk[r] = f2bf(fmaxf(v, 0.f));
                }
                int phys = (h0 >> 3) ^ (m & 7);
                *(u16x4*)&sA[m * 128 + phys * 8 + (h0 & 7)] = pk;
            }
        }
        __syncthreads();

        // layer 2: C2[m][j] = h1L[m][:] . W2[:, j]
        f32x4 acc2[2][4] = {};
#pragma unroll
        for (int ks = 0; ks < 4; ++ks) {
            bf16x8 a2[2], b2[4];
#pragma unroll
            for (int s = 0; s < 2; ++s) {
                int m = wave * 32 + s * 16 + l15;
                int phys = (ks * 4 + quad) ^ (m & 7);
                a2[s] = *(const bf16x8*)&sA[m * 128 + phys * 8];
            }
#pragma unroll
            for (int t = 0; t < 4; ++t) {
                int j = t * 16 + l15;
                int phys = (ks * 4 + quad) ^ (j & 7);
                b2[t] = *(const bf16x8*)&sW2[j * 128 + phys * 8];
            }
#pragma unroll
            for (int s = 0; s < 2; ++s)
#pragma unroll
                for (int t = 0; t < 4; ++t)
                    acc2[s][t] = MFMA16(a2[s], b2[t], acc2[s][t]);
        }

        // layer 3 + sigmoid
        float b2v[4], w3v[4];
#pragma unroll
        for (int t = 0; t < 4; ++t) {
            int j = t * 16 + l15;
            b2v[t] = eb2[e * 64 + j];
            w3v[t] = eW3[e * 64 + j];
        }
        float be3 = eb3[e];
#pragma unroll
        for (int s = 0; s < 2; ++s) {
            float sv[4] = {0.f, 0.f, 0.f, 0.f};
#pragma unroll
            for (int t = 0; t < 4; ++t)
#pragma unroll
                for (int r = 0; r < 4; ++r) {
                    float v = acc2[s][t][r] + b2v[t];
                    sv[r] += fmaxf(v, 0.f) * w3v[t];
                }
#pragma unroll
            for (int mask = 1; mask < 16; mask <<= 1)
#pragma unroll
                for (int r = 0; r < 4; ++r) sv[r] += __shfl_xor(sv[r], mask, 64);
            if (l15 == 0) {
#pragma unroll
                for (int r = 0; r < 4; ++r) {
                    int m = wave * 32 + s * 16 + quad * 4 + r;
                    float z = sv[r] + be3;
                    out_eo[(size_t)(rb * 128 + m) * 16 + e] = 1.f / (1.f + __expf(-z));
                }
            }
        }
    } else {
        // ------------------------- router path -------------------------
        char* region0 = smem;                        // stage xs 16KB | rw1 8KB; then h_r[128][68] f32
        float* h2s = (float*)(smem + 34816);         // [128][36]
        u16* xs_l = (u16*)region0;
        u16* rw_l = (u16*)(region0 + 16384);
        float* h_r = (float*)region0;
        int rb = blockIdx.x;

        f32x4 acc[4][2] = {};
        const u16* xg_base = xs_g + (size_t)rb * 131072;

        for (int kc = 0; kc < 16; ++kc) {
            const u16* xg = xg_base + kc * 8192;
            const u16* rg = rw1s + kc * 4096;
            int so = wave * 2048;
#pragma unroll
            for (int i = 0; i < 4; ++i)
                gload16(xg + so + i * 512 + lane * 8, &xs_l[so + i * 512]);
            int so2 = wave * 1024;
#pragma unroll
            for (int i = 0; i < 2; ++i)
                gload16(rg + so2 + i * 512 + lane * 8, &rw_l[so2 + i * 512]);
            __syncthreads();
#pragma unroll
            for (int ks = 0; ks < 2; ++ks) {
                bf16x8 af[4], bfr[2];
#pragma unroll
                for (int s = 0; s < 4; ++s) {
                    int j = s * 16 + l15;
                    int phys = (ks * 4 + quad) ^ (j & 7);
                    af[s] = *(const bf16x8*)&rw_l[j * 64 + phys * 8];
                }
#pragma unroll
                for (int t = 0; t < 2; ++t) {
                    int m = wave * 32 + t * 16 + l15;
                    int phys = (ks * 4 + quad) ^ (m & 7);
                    bfr[t] = *(const bf16x8*)&xs_l[m * 64 + phys * 8];
                }
#pragma unroll
                for (int s = 0; s < 4; ++s)
#pragma unroll
                    for (int t = 0; t < 2; ++t)
                        acc[s][t] = MFMA16(af[s], bfr[t], acc[s][t]);
            }
            __syncthreads();
        }

        // epilogue: h_r[m][j] fp32 (stride 68)
#pragma unroll
        for (int s = 0; s < 4; ++s) {
            int j0 = s * 16 + quad * 4;
            float4 bv = *(const float4*)&rb1e[j0];
#pragma unroll
            for (int t = 0; t < 2; ++t) {
                int m = wave * 32 + t * 16 + l15;
                float4 hv;
                hv.x = fmaxf(acc[s][t][0] + bv.x, 0.f);
                hv.y = fmaxf(acc[s][t][1] + bv.y, 0.f);
                hv.z = fmaxf(acc[s][t][2] + bv.z, 0.f);
                hv.w = fmaxf(acc[s][t][3] + bv.w, 0.f);
                *(float4*)&h_r[m * 68 + j0] = hv;
            }
        }
        __syncthreads();

        // layer 2 (64->32), fp32 VALU
        {
            int m = tid & 127, qg = tid >> 7;
            float h2r[16];
#pragma unroll
            for (int k = 0; k < 16; ++k) h2r[k] = 0.f;
            for (int i = 0; i < 64; ++i) {
                float hv = h_r[m * 68 + i];
                const float4* wrow = (const float4*)&rW2[i * 32 + qg * 16];
                float w[16];
                *(float4*)&w[0] = wrow[0];
                *(float4*)&w[4] = wrow[1];
                *(float4*)&w[8] = wrow[2];
                *(float4*)&w[12] = wrow[3];
#pragma unroll
                for (int k = 0; k < 16; ++k) h2r[k] += hv * w[k];
            }
#pragma unroll
            for (int k = 0; k < 16; ++k)
                h2r[k] = fmaxf(h2r[k] + rb2[qg * 16 + k], 0.f);
#pragma unroll
            for (int k = 0; k < 16; k += 4)
                *(float4*)&h2s[m * 36 + qg * 16 + k] = *(float4*)&h2r[k];
        }
        __syncthreads();

        // layer 3 (32->16) + softmax
        if (tid < 128) {
            int mm = tid;
            float lg[16];
#pragma unroll
            for (int o = 0; o < 16; ++o) lg[o] = 0.f;
            for (int q = 0; q < 32; ++q) {
                float hv = h2s[mm * 36 + q];
                const float4* wr = (const float4*)&rW3[q * 16];
                float w[16];
                *(float4*)&w[0] = wr[0];
                *(float4*)&w[4] = wr[1];
                *(float4*)&w[8] = wr[2];
                *(float4*)&w[12] = wr[3];
#pragma unroll
                for (int o = 0; o < 16; ++o) lg[o] += hv * w[o];
            }
#pragma unroll
            for (int o = 0; o < 16; ++o) lg[o] += rb3[o];
            float mx = lg[0];
#pragma unroll
            for (int o = 1; o < 16; ++o) mx = fmaxf(mx, lg[o]);
            float ss = 0.f;
#pragma unroll
            for (int o = 0; o < 16; ++o) { lg[o] = __expf(lg[o] - mx); ss += lg[o]; }
            float inv = 1.f / ss;
            size_t base = (size_t)(rb * 128 + mm) * 16;
#pragma unroll
            for (int o = 0; o < 16; o += 4) {
                float4 v;
                v.x = lg[o] * inv; v.y = lg[o + 1] * inv;
                v.z = lg[o + 2] * inv; v.w = lg[o + 3] * inv;
                *(float4*)&out_rw[base + o] = v;
            }
        }
    }
}

// weighted_pred[b] = sum_e rw[b][e]*eo[b][e]
__global__ void combine_kernel(const float* __restrict__ rw, const float* __restrict__ eo,
                               float* __restrict__ wp) {
    int b = blockIdx.x * 256 + threadIdx.x;
    const float4* r4 = (const float4*)(rw + (size_t)b * 16);
    const float4* o4 = (const float4*)(eo + (size_t)b * 16);
    float s = 0.f;
#pragma unroll
    for (int k = 0; k < 4; ++k) {
        float4 r = r4[k], o = o4[k];
        s += r.x * o.x + r.y * o.y + r.z * o.z + r.w * o.w;
    }
    wp[b] = s;
}

// ---------------------------------------------------------------------------

extern "C" void kernel_launch(void* const* d_in, const int* in_sizes, int n_in,
                              void* d_out, int out_size, void* d_ws, size_t ws_size,
                              hipStream_t stream) {
    const float* x       = (const float*)d_in[0];
    const float* r_gamma = (const float*)d_in[1];
    const float* r_beta  = (const float*)d_in[2];
    const float* r_mean  = (const float*)d_in[3];
    const float* r_var   = (const float*)d_in[4];
    const float* rW1     = (const float*)d_in[5];
    const float* rb1     = (const float*)d_in[6];
    const float* rW2     = (const float*)d_in[7];
    const float* rb2     = (const float*)d_in[8];
    const float* rW3     = (const float*)d_in[9];
    const float* rb3     = (const float*)d_in[10];
    const float* e_gamma = (const float*)d_in[11];
    const float* e_beta  = (const float*)d_in[12];
    const float* e_mean  = (const float*)d_in[13];
    const float* e_var   = (const float*)d_in[14];
    const float* eW1     = (const float*)d_in[15];
    const float* eb1     = (const float*)d_in[16];
    const float* eW2     = (const float*)d_in[17];
    const float* eb2     = (const float*)d_in[18];
    const float* eW3     = (const float*)d_in[19];
    const float* eb3     = (const float*)d_in[20];

    char* ws = (char*)d_ws;
    u16* xs_g   = (u16*)ws;                          // 134217728 B
    u16* w1s    = (u16*)(ws + 134217728);            // 4194304 B
    u16* rw1s   = (u16*)(ws + 138412032);            // 131072 B
    u16* w2s    = (u16*)(ws + 138543104);            // 262144 B
    float* b1e  = (float*)(ws + 138805248);          // 8192 B
    float* rb1e = (float*)(ws + 138813440);          // 256 B

    float* out_wp = (float*)d_out;
    float* out_rw = out_wp + B_ROWS;
    float* out_eo = out_rw + (size_t)B_ROWS * NE;

    prep_all<<<34416, 256, 0, stream>>>(
        x, xs_g,
        eW1, e_gamma, e_beta, e_mean, e_var, eb1, w1s, b1e,
        rW1, r_gamma, r_beta, r_mean, r_var, rb1, rw1s, rb1e,
        eW2, w2s);

    fused_main<<<8704, 256, 0, stream>>>(
        xs_g, w1s, b1e, w2s, eb2, eW3, eb3, out_eo,
        rw1s, rb1e, rW2, rb2, rW3, rb3, out_rw);

    combine_kernel<<<256, 256, 0, stream>>>(out_rw, out_eo, out_wp);
}

// Round 3
// 779.802 us; speedup vs baseline: 1.0198x; 1.0136x over previous
//
#include <hip/hip_runtime.h>

// ---------------------------------------------------------------------------
// FairnessBranch: router (BN->MLP->softmax) + 16 experts (BN folded ->
// D->128->64->1 sigmoid), weighted sum.  B=65536 D=1024 E=16.
//
// R3: prep_x rewritten as LDS-bounce transpose. Old version wrote 128 B
// chunks at 16 KB stride (DRAM page thrash, ~1.1 TB/s). New: per block
// 16 rows x 1024 cols -> dense 64 KB read, convert, LDS (32 KB, swizzled
// layout), then lane-linear streaming stores (1 KB contiguous per wave).
// Output bytes identical to R2. fused_main / combine unchanged.
// ---------------------------------------------------------------------------

typedef unsigned short u16;
typedef __attribute__((ext_vector_type(8))) short bf16x8;
typedef __attribute__((ext_vector_type(4))) float f32x4;
typedef __attribute__((ext_vector_type(8))) unsigned short u16x8;
typedef __attribute__((ext_vector_type(4))) unsigned short u16x4;

#define MFMA16(a, b, c) __builtin_amdgcn_mfma_f32_16x16x32_bf16(a, b, c, 0, 0, 0)

#define B_ROWS 65536
#define DIM 1024
#define NE 16
#define EPS 1e-5f

// fp32 -> bf16 round-to-nearest-even
__device__ inline u16 f2bf(float f) {
    union { float f; unsigned u; } c; c.f = f;
    unsigned u = c.u;
    return (u16)((u + 0x7fffu + ((u >> 16) & 1u)) >> 16);
}

// async global->LDS, 16B per lane. lds dest must be wave-uniform base.
__device__ inline void gload16(const u16* g, u16* s) {
    __builtin_amdgcn_global_load_lds(
        (const __attribute__((address_space(1))) unsigned int*)g,
        (__attribute__((address_space(3))) unsigned int*)s,
        16, 0, 0);
}

// ---------------------------------------------------------------------------
// prep bodies
// ---------------------------------------------------------------------------

// x [B][D] fp32 -> bf16, tiled [rb(512)][kc(16)][r(128)][64] with 16B-block
// XOR swizzle (phys_blk = logical_blk ^ (r&7)). LDS-bounce version:
// block = 16 rows; phase1 dense read + convert + LDS in swizzled layout;
// phase2 lane-linear LDS read -> 1KB/wave contiguous global stores.
__device__ void body_prep_x(int blk, int tid, const float* __restrict__ x,
                            u16* __restrict__ xs_g, u16* __restrict__ lds) {
    int p = tid & 15, rloc = tid >> 4;          // 16 octet-groups x 16 rows
    int r_g = blk * 16 + rloc;
    int r = r_g & 127;
    int lb = p & 7;
    int phys = lb ^ (r & 7);
    const float* xrow = x + (size_t)r_g * 1024;
#pragma unroll
    for (int i = 0; i < 8; ++i) {
        int kc = 2 * i + (p >> 3);
        int c = kc * 64 + lb * 8;
        float4 f0 = *(const float4*)(xrow + c);
        float4 f1 = *(const float4*)(xrow + c + 4);
        u16x8 u;
        u[0] = f2bf(f0.x); u[1] = f2bf(f0.y); u[2] = f2bf(f0.z); u[3] = f2bf(f0.w);
        u[4] = f2bf(f1.x); u[5] = f2bf(f1.y); u[6] = f2bf(f1.z); u[7] = f2bf(f1.w);
        *(u16x8*)&lds[(kc * 16 + rloc) * 64 + phys * 8] = u;
    }
    __syncthreads();
    int rb = blk >> 3, R0 = (blk & 7) * 16;
    int tl = tid & 127, th = tid >> 7;
#pragma unroll
    for (int jj = 0; jj < 8; ++jj) {
        int kc = 2 * jj + th;
        u16x8 v = *(const u16x8*)&lds[kc * 1024 + tl * 8];
        *(u16x8*)&xs_g[(((size_t)(rb * 16 + kc) * 128 + R0 + (tl >> 3)) << 6) + (tl & 7) * 8] = v;
    }
}

// W1_eff^T bf16: w1s[e][kc][h(128)][64 swizzled]
__device__ void body_prep_w1s(int t, const float* __restrict__ eW1, const float* __restrict__ eg,
                              const float* __restrict__ ev, u16* __restrict__ w1s) {
    int p = t & 7, r = (t >> 3) & 127, kc = (t >> 10) & 15, e = t >> 14;
    int lb = p ^ (r & 7);
    u16x8 u;
#pragma unroll
    for (int j = 0; j < 8; ++j) {
        int d = kc * 64 + lb * 8 + j;
        float sc = eg[e * 1024 + d] * rsqrtf(ev[e * 1024 + d] + EPS);
        u[j] = f2bf(eW1[((size_t)e * 1024 + d) * 128 + r] * sc);
    }
    *(u16x8*)&w1s[((size_t)((e * 16 + kc) * 128 + r) << 6) + p * 8] = u;
}

// b1_eff[e][h] = eb1 + sum_d shift[e][d]*eW1[e][d][h]; one wave per (e,h)
__device__ void body_prep_b1(int g, int lane, const float* __restrict__ eW1,
                             const float* __restrict__ eg, const float* __restrict__ eb,
                             const float* __restrict__ em, const float* __restrict__ ev,
                             const float* __restrict__ eb1, float* __restrict__ b1e) {
    int e = g >> 7, h = g & 127;
    float s = 0.f;
    for (int d = lane; d < 1024; d += 64) {
        float sc = eg[e * 1024 + d] * rsqrtf(ev[e * 1024 + d] + EPS);
        float sh = eb[e * 1024 + d] - em[e * 1024 + d] * sc;
        s += sh * eW1[((size_t)e * 1024 + d) * 128 + h];
    }
#pragma unroll
    for (int m = 1; m < 64; m <<= 1) s += __shfl_xor(s, m, 64);
    if (lane == 0) b1e[e * 128 + h] = eb1[e * 128 + h] + s;
}

// router W1_eff^T bf16: rw1s[kc][j(64)][64 swizzled]
__device__ void body_prep_rw1s(int t, const float* __restrict__ rW1, const float* __restrict__ rg,
                               const float* __restrict__ rv, u16* __restrict__ rw1s) {
    int p = t & 7, r = (t >> 3) & 63, kc = t >> 9;
    int lb = p ^ (r & 7);
    u16x8 u;
#pragma unroll
    for (int j = 0; j < 8; ++j) {
        int d = kc * 64 + lb * 8 + j;
        float sc = rg[d] * rsqrtf(rv[d] + EPS);
        u[j] = f2bf(rW1[d * 64 + r] * sc);
    }
    *(u16x8*)&rw1s[((kc * 64 + r) << 6) + p * 8] = u;
}

// rb1_eff[j] = rb1[j] + sum_d shift[d]*rW1[d][j]; one wave per j
__device__ void body_prep_rb1(int j, int lane, const float* __restrict__ rW1,
                              const float* __restrict__ rg, const float* __restrict__ rbta,
                              const float* __restrict__ rm, const float* __restrict__ rv,
                              const float* __restrict__ rb1, float* __restrict__ rb1e) {
    float s = 0.f;
    for (int d = lane; d < 1024; d += 64) {
        float sc = rg[d] * rsqrtf(rv[d] + EPS);
        float sh = rbta[d] - rm[d] * sc;
        s += sh * rW1[d * 64 + j];
    }
#pragma unroll
    for (int m = 1; m < 64; m <<= 1) s += __shfl_xor(s, m, 64);
    if (lane == 0) rb1e[j] = rb1[j] + s;
}

// W2^T bf16: w2s[e][j(64)][128 swizzled]
__device__ void body_prep_w2s(int t, const float* __restrict__ eW2, u16* __restrict__ w2s) {
    int p = t & 15, j = (t >> 4) & 63, e = t >> 10;
    int lb = p ^ (j & 7);
    int h0 = lb * 8;
    u16x8 u;
#pragma unroll
    for (int jj = 0; jj < 8; ++jj)
        u[jj] = f2bf(eW2[((size_t)e * 128 + h0 + jj) * 64 + j]);
    *(u16x8*)&w2s[((e * 64 + j) << 7) + p * 8] = u;
}

// grid layout: [0,4096) prep_x | [4096,5120) w1s | [5120,5632) b1
//              [5632,5664) rw1s | [5664,5680) rb1 | [5680,5744) w2s
__global__ __launch_bounds__(256) void prep_all(
    const float* __restrict__ x, u16* __restrict__ xs_g,
    const float* __restrict__ eW1, const float* __restrict__ eg,
    const float* __restrict__ eb, const float* __restrict__ em,
    const float* __restrict__ ev, const float* __restrict__ eb1,
    u16* __restrict__ w1s, float* __restrict__ b1e,
    const float* __restrict__ rW1, const float* __restrict__ rg,
    const float* __restrict__ rbta, const float* __restrict__ rm,
    const float* __restrict__ rv, const float* __restrict__ rb1,
    u16* __restrict__ rw1s, float* __restrict__ rb1e,
    const float* __restrict__ eW2, u16* __restrict__ w2s) {
    __shared__ __align__(16) u16 lds[16384];   // 32KB bounce buffer (prep_x only)
    int bid = blockIdx.x, tid = threadIdx.x;
    if (bid < 4096) {
        body_prep_x(bid, tid, x, xs_g, lds);
    } else if (bid < 5120) {
        body_prep_w1s((bid - 4096) * 256 + tid, eW1, eg, ev, w1s);
    } else if (bid < 5632) {
        body_prep_b1((bid - 5120) * 4 + (tid >> 6), tid & 63, eW1, eg, eb, em, ev, eb1, b1e);
    } else if (bid < 5664) {
        body_prep_rw1s((bid - 5632) * 256 + tid, rW1, rg, rv, rw1s);
    } else if (bid < 5680) {
        body_prep_rb1((bid - 5664) * 4 + (tid >> 6), tid & 63, rW1, rg, rbta, rm, rv, rb1, rb1e);
    } else {
        body_prep_w2s((bid - 5680) * 256 + tid, eW2, w2s);
    }
}

// ---------------------------------------------------------------------------
// fused main kernel: blocks [0,512) router, [512,8704) experts.
// ---------------------------------------------------------------------------
__global__ __launch_bounds__(256) void fused_main(
    const u16* __restrict__ xs_g, const u16* __restrict__ w1s,
    const float* __restrict__ b1e, const u16* __restrict__ w2s,
    const float* __restrict__ eb2, const float* __restrict__ eW3,
    const float* __restrict__ eb3, float* __restrict__ out_eo,
    const u16* __restrict__ rw1s, const float* __restrict__ rb1e,
    const float* __restrict__ rW2, const float* __restrict__ rb2,
    const float* __restrict__ rW3, const float* __restrict__ rb3,
    float* __restrict__ out_rw) {
    // union: expert uses 48KB (sA 32K | sW2 16K); router uses 52KB
    // (staging/h_r 34816 | h2s 18432). 53248B -> 3 blocks/CU either way.
    __shared__ __align__(16) char smem[53248];

    int tid = threadIdx.x;
    int wave = tid >> 6, lane = tid & 63;
    int quad = lane >> 4, l15 = lane & 15;

    if (blockIdx.x >= 512) {
        // ------------------------- expert path -------------------------
        u16* sA = (u16*)smem;             // 32KB: xs[8192] | wt[8192]; then h1L[128][128]
        u16* sW2 = (u16*)(smem + 32768);  // 16KB: w2t[64][128]
        int bid = blockIdx.x - 512;
        int e = bid & 15, rb = bid >> 4;
        int wm = wave & 1, wn = wave >> 1;

        f32x4 acc[4][4] = {};
        const u16* xg_base = xs_g + (size_t)rb * 131072;
        const u16* wg_base = w1s + (size_t)e * 131072;

        for (int kc = 0; kc < 16; ++kc) {
            const u16* xg = xg_base + kc * 8192;
            const u16* wg = wg_base + kc * 8192;
            int so = wave * 2048;
#pragma unroll
            for (int i = 0; i < 4; ++i) {
                gload16(xg + so + i * 512 + lane * 8, &sA[so + i * 512]);
                gload16(wg + so + i * 512 + lane * 8, &sA[8192 + so + i * 512]);
            }
            __syncthreads();
#pragma unroll
            for (int ks = 0; ks < 2; ++ks) {
                bf16x8 af[4], bfr[4];
#pragma unroll
                for (int s = 0; s < 4; ++s) {
                    int h = wm * 64 + s * 16 + l15;
                    int phys = (ks * 4 + quad) ^ (h & 7);
                    af[s] = *(const bf16x8*)&sA[8192 + h * 64 + phys * 8];
                }
#pragma unroll
                for (int t = 0; t < 4; ++t) {
                    int m = wn * 64 + t * 16 + l15;
                    int phys = (ks * 4 + quad) ^ (m & 7);
                    bfr[t] = *(const bf16x8*)&sA[m * 64 + phys * 8];
                }
#pragma unroll
                for (int s = 0; s < 4; ++s)
#pragma unroll
                    for (int t = 0; t < 4; ++t)
                        acc[s][t] = MFMA16(af[s], bfr[t], acc[s][t]);
            }
            __syncthreads();
        }

        // stage W2t (async, waited by next barrier)
        {
            const u16* wg2 = w2s + e * 8192;
            int so = wave * 2048;
#pragma unroll
            for (int i = 0; i < 4; ++i)
                gload16(wg2 + so + i * 512 + lane * 8, &sW2[so + i * 512]);
        }
        // h1L[m][h] = relu(acc + b1), bf16 packed 4
#pragma unroll
        for (int s = 0; s < 4; ++s) {
            int h0 = wm * 64 + s * 16 + quad * 4;
            float4 bv = *(const float4*)&b1e[e * 128 + h0];
            float bva[4] = {bv.x, bv.y, bv.z, bv.w};
#pragma unroll
            for (int t = 0; t < 4; ++t) {
                int m = wn * 64 + t * 16 + l15;
                u16x4 pk;
#pragma unroll
                for (int r = 0; r < 4; ++r) {
                    float v = acc[s][t][r] + bva[r];
                    pk[r] = f2bf(fmaxf(v, 0.f));
                }
                int phys = (h0 >> 3) ^ (m & 7);
                *(u16x4*)&sA[m * 128 + phys * 8 + (h0 & 7)] = pk;
            }
        }
        __syncthreads();

        // layer 2: C2[m][j] = h1L[m][:] . W2[:, j]
        f32x4 acc2[2][4] = {};
#pragma unroll
        for (int ks = 0; ks < 4; ++ks) {
            bf16x8 a2[2], b2[4];
#pragma unroll
            for (int s = 0; s < 2; ++s) {
                int m = wave * 32 + s * 16 + l15;
                int phys = (ks * 4 + quad) ^ (m & 7);
                a2[s] = *(const bf16x8*)&sA[m * 128 + phys * 8];
            }
#pragma unroll
            for (int t = 0; t < 4; ++t) {
                int j = t * 16 + l15;
                int phys = (ks * 4 + quad) ^ (j & 7);
                b2[t] = *(const bf16x8*)&sW2[j * 128 + phys * 8];
            }
#pragma unroll
            for (int s = 0; s < 2; ++s)
#pragma unroll
                for (int t = 0; t < 4; ++t)
                    acc2[s][t] = MFMA16(a2[s], b2[t], acc2[s][t]);
        }

        // layer 3 + sigmoid
        float b2v[4], w3v[4];
#pragma unroll
        for (int t = 0; t < 4; ++t) {
            int j = t * 16 + l15;
            b2v[t] = eb2[e * 64 + j];
            w3v[t] = eW3[e * 64 + j];
        }
        float be3 = eb3[e];
#pragma unroll
        for (int s = 0; s < 2; ++s) {
            float sv[4] = {0.f, 0.f, 0.f, 0.f};
#pragma unroll
            for (int t = 0; t < 4; ++t)
#pragma unroll
                for (int r = 0; r < 4; ++r) {
                    float v = acc2[s][t][r] + b2v[t];
                    sv[r] += fmaxf(v, 0.f) * w3v[t];
                }
#pragma unroll
            for (int mask = 1; mask < 16; mask <<= 1)
#pragma unroll
                for (int r = 0; r < 4; ++r) sv[r] += __shfl_xor(sv[r], mask, 64);
            if (l15 == 0) {
#pragma unroll
                for (int r = 0; r < 4; ++r) {
                    int m = wave * 32 + s * 16 + quad * 4 + r;
                    float z = sv[r] + be3;
                    out_eo[(size_t)(rb * 128 + m) * 16 + e] = 1.f / (1.f + __expf(-z));
                }
            }
        }
    } else {
        // ------------------------- router path -------------------------
        char* region0 = smem;                        // stage xs 16KB | rw1 8KB; then h_r[128][68] f32
        float* h2s = (float*)(smem + 34816);         // [128][36]
        u16* xs_l = (u16*)region0;
        u16* rw_l = (u16*)(region0 + 16384);
        float* h_r = (float*)region0;
        int rb = blockIdx.x;

        f32x4 acc[4][2] = {};
        const u16* xg_base = xs_g + (size_t)rb * 131072;

        for (int kc = 0; kc < 16; ++kc) {
            const u16* xg = xg_base + kc * 8192;
            const u16* rg = rw1s + kc * 4096;
            int so = wave * 2048;
#pragma unroll
            for (int i = 0; i < 4; ++i)
                gload16(xg + so + i * 512 + lane * 8, &xs_l[so + i * 512]);
            int so2 = wave * 1024;
#pragma unroll
            for (int i = 0; i < 2; ++i)
                gload16(rg + so2 + i * 512 + lane * 8, &rw_l[so2 + i * 512]);
            __syncthreads();
#pragma unroll
            for (int ks = 0; ks < 2; ++ks) {
                bf16x8 af[4], bfr[2];
#pragma unroll
                for (int s = 0; s < 4; ++s) {
                    int j = s * 16 + l15;
                    int phys = (ks * 4 + quad) ^ (j & 7);
                    af[s] = *(const bf16x8*)&rw_l[j * 64 + phys * 8];
                }
#pragma unroll
                for (int t = 0; t < 2; ++t) {
                    int m = wave * 32 + t * 16 + l15;
                    int phys = (ks * 4 + quad) ^ (m & 7);
                    bfr[t] = *(const bf16x8*)&xs_l[m * 64 + phys * 8];
                }
#pragma unroll
                for (int s = 0; s < 4; ++s)
#pragma unroll
                    for (int t = 0; t < 2; ++t)
                        acc[s][t] = MFMA16(af[s], bfr[t], acc[s][t]);
            }
            __syncthreads();
        }

        // epilogue: h_r[m][j] fp32 (stride 68)
#pragma unroll
        for (int s = 0; s < 4; ++s) {
            int j0 = s * 16 + quad * 4;
            float4 bv = *(const float4*)&rb1e[j0];
#pragma unroll
            for (int t = 0; t < 2; ++t) {
                int m = wave * 32 + t * 16 + l15;
                float4 hv;
                hv.x = fmaxf(acc[s][t][0] + bv.x, 0.f);
                hv.y = fmaxf(acc[s][t][1] + bv.y, 0.f);
                hv.z = fmaxf(acc[s][t][2] + bv.z, 0.f);
                hv.w = fmaxf(acc[s][t][3] + bv.w, 0.f);
                *(float4*)&h_r[m * 68 + j0] = hv;
            }
        }
        __syncthreads();

        // layer 2 (64->32), fp32 VALU
        {
            int m = tid & 127, qg = tid >> 7;
            float h2r[16];
#pragma unroll
            for (int k = 0; k < 16; ++k) h2r[k] = 0.f;
            for (int i = 0; i < 64; ++i) {
                float hv = h_r[m * 68 + i];
                const float4* wrow = (const float4*)&rW2[i * 32 + qg * 16];
                float w[16];
                *(float4*)&w[0] = wrow[0];
                *(float4*)&w[4] = wrow[1];
                *(float4*)&w[8] = wrow[2];
                *(float4*)&w[12] = wrow[3];
#pragma unroll
                for (int k = 0; k < 16; ++k) h2r[k] += hv * w[k];
            }
#pragma unroll
            for (int k = 0; k < 16; ++k)
                h2r[k] = fmaxf(h2r[k] + rb2[qg * 16 + k], 0.f);
#pragma unroll
            for (int k = 0; k < 16; k += 4)
                *(float4*)&h2s[m * 36 + qg * 16 + k] = *(float4*)&h2r[k];
        }
        __syncthreads();

        // layer 3 (32->16) + softmax
        if (tid < 128) {
            int mm = tid;
            float lg[16];
#pragma unroll
            for (int o = 0; o < 16; ++o) lg[o] = 0.f;
            for (int q = 0; q < 32; ++q) {
                float hv = h2s[mm * 36 + q];
                const float4* wr = (const float4*)&rW3[q * 16];
                float w[16];
                *(float4*)&w[0] = wr[0];
                *(float4*)&w[4] = wr[1];
                *(float4*)&w[8] = wr[2];
                *(float4*)&w[12] = wr[3];
#pragma unroll
                for (int o = 0; o < 16; ++o) lg[o] += hv * w[o];
            }
#pragma unroll
            for (int o = 0; o < 16; ++o) lg[o] += rb3[o];
            float mx = lg[0];
#pragma unroll
            for (int o = 1; o < 16; ++o) mx = fmaxf(mx, lg[o]);
            float ss = 0.f;
#pragma unroll
            for (int o = 0; o < 16; ++o) { lg[o] = __expf(lg[o] - mx); ss += lg[o]; }
            float inv = 1.f / ss;
            size_t base = (size_t)(rb * 128 + mm) * 16;
#pragma unroll
            for (int o = 0; o < 16; o += 4) {
                float4 v;
                v.x = lg[o] * inv; v.y = lg[o + 1] * inv;
                v.z = lg[o + 2] * inv; v.w = lg[o + 3] * inv;
                *(float4*)&out_rw[base + o] = v;
            }
        }
    }
}

// weighted_pred[b] = sum_e rw[b][e]*eo[b][e]
__global__ void combine_kernel(const float* __restrict__ rw, const float* __restrict__ eo,
                               float* __restrict__ wp) {
    int b = blockIdx.x * 256 + threadIdx.x;
    const float4* r4 = (const float4*)(rw + (size_t)b * 16);
    const float4* o4 = (const float4*)(eo + (size_t)b * 16);
    float s = 0.f;
#pragma unroll
    for (int k = 0; k < 4; ++k) {
        float4 r = r4[k], o = o4[k];
        s += r.x * o.x + r.y * o.y + r.z * o.z + r.w * o.w;
    }
    wp[b] = s;
}

// ---------------------------------------------------------------------------

extern "C" void kernel_launch(void* const* d_in, const int* in_sizes, int n_in,
                              void* d_out, int out_size, void* d_ws, size_t ws_size,
                              hipStream_t stream) {
    const float* x       = (const float*)d_in[0];
    const float* r_gamma = (const float*)d_in[1];
    const float* r_beta  = (const float*)d_in[2];
    const float* r_mean  = (const float*)d_in[3];
    const float* r_var   = (const float*)d_in[4];
    const float* rW1     = (const float*)d_in[5];
    const float* rb1     = (const float*)d_in[6];
    const float* rW2     = (const float*)d_in[7];
    const float* rb2     = (const float*)d_in[8];
    const float* rW3     = (const float*)d_in[9];
    const float* rb3     = (const float*)d_in[10];
    const float* e_gamma = (const float*)d_in[11];
    const float* e_beta  = (const float*)d_in[12];
    const float* e_mean  = (const float*)d_in[13];
    const float* e_var   = (const float*)d_in[14];
    const float* eW1     = (const float*)d_in[15];
    const float* eb1     = (const float*)d_in[16];
    const float* eW2     = (const float*)d_in[17];
    const float* eb2     = (const float*)d_in[18];
    const float* eW3     = (const float*)d_in[19];
    const float* eb3     = (const float*)d_in[20];

    char* ws = (char*)d_ws;
    u16* xs_g   = (u16*)ws;                          // 134217728 B
    u16* w1s    = (u16*)(ws + 134217728);            // 4194304 B
    u16* rw1s   = (u16*)(ws + 138412032);            // 131072 B
    u16* w2s    = (u16*)(ws + 138543104);            // 262144 B
    float* b1e  = (float*)(ws + 138805248);          // 8192 B
    float* rb1e = (float*)(ws + 138813440);          // 256 B

    float* out_wp = (float*)d_out;
    float* out_rw = out_wp + B_ROWS;
    float* out_eo = out_rw + (size_t)B_ROWS * NE;

    prep_all<<<5744, 256, 0, stream>>>(
        x, xs_g,
        eW1, e_gamma, e_beta, e_mean, e_var, eb1, w1s, b1e,
        rW1, r_gamma, r_beta, r_mean, r_var, rb1, rw1s, rb1e,
        eW2, w2s);

    fused_main<<<8704, 256, 0, stream>>>(
        xs_g, w1s, b1e, w2s, eb2, eW3, eb3, out_eo,
        rw1s, rb1e, rW2, rb2, rW3, rb3, out_rw);

    combine_kernel<<<256, 256, 0, stream>>>(out_rw, out_eo, out_wp);
}